// Round 1
// baseline (285.587 us; speedup 1.0000x reference)
//
#include <hip/hip_runtime.h>

// Problem: Embedding_6940667150787
//   idx:      [131072] int32 in [0, 198)
//   wordlist: [198, 512] float32
//   out:      [131072, 512] float32 = wordlist[idx] + positional_encoding
//
// PE: for j in 0..254: angle = i / 10000^(2j/512);
//     pe[i, 2j] = sin(angle), pe[i, 2j+1] = cos(angle); cols 510,511 = 0.
//
// Memory-bound: 256 MiB output write dominates. One thread per float4 of
// output (covers column pairs j=2c and j=2c+1), coalesced 16B stores.

#define L_TOTAL 131072
#define VEC_PER_ROW 128   // 512 floats / 4

__device__ __forceinline__ void sincos_fast(float a, float& s, float& c) {
    // Exact-enough argument reduction by 2*pi (Cody-Waite, FMA), then the
    // hardware transcendental which takes REVOLUTIONS in [-0.5, 0.5].
    const float INV2PI = 0.15915493667125702f;        // float(1/(2*pi))
    const float PI2_HI = 6.2831854820251465f;         // hi split of 2*pi
    const float PI2_LO = -1.7484555314695172e-7f;     // 2*pi - PI2_HI
    float k = rintf(a * INV2PI);                      // whole revolutions (exact in fp32, k <= ~2.1e4)
    float r = fmaf(-k, PI2_HI, a);                    // exact product inside fma
    r = fmaf(-k, PI2_LO, r);                          // r in ~[-pi, pi], err ~4e-7 rad
    float rev = r * INV2PI;                           // revolutions, small
    s = __builtin_amdgcn_sinf(rev);                   // v_sin_f32: sin(rev * 2*pi)
    c = __builtin_amdgcn_cosf(rev);                   // v_cos_f32
}

__global__ __launch_bounds__(256) void embed_pe_kernel(
    const int* __restrict__ idx,
    const float* __restrict__ wordlist,
    float* __restrict__ out)
{
    int g = blockIdx.x * 256 + threadIdx.x;  // 0 .. 131072*128-1
    int i = g >> 7;                          // row (sequence position)
    int c = g & 127;                         // float4 column within row

    // Gather token embedding: 128 consecutive threads share idx[i] (L1 hit),
    // wordlist rows are 396 KB total -> cached; loads coalesced in c.
    int token = idx[i];
    const float4 w = ((const float4*)wordlist)[token * VEC_PER_ROW + c];

    // Pair indices covered by this float4: j0 = 2c (cols 4c,4c+1), j1 = 2c+1.
    const float K = 0.051905126483205076f;   // log2(10000) / 256
    float j0 = (float)(2 * c);
    float j1 = (float)(2 * c + 1);
    float invf0 = exp2f(-j0 * K);            // 10000^(-2*j0/512)
    float invf1 = exp2f(-j1 * K);
    float fi = (float)i;
    float a0 = fi * invf0;
    float a1 = fi * invf1;

    float s0, c0, s1, c1;
    sincos_fast(a0, s0, c0);
    sincos_fast(a1, s1, c1);
    if (c == VEC_PER_ROW - 1) {              // j1 == 255 -> cols 510,511 have no PE
        s1 = 0.0f;
        c1 = 0.0f;
    }

    float4 o;
    o.x = w.x + s0;
    o.y = w.y + c0;
    o.z = w.z + s1;
    o.w = w.w + c1;
    ((float4*)out)[g] = o;
}

extern "C" void kernel_launch(void* const* d_in, const int* in_sizes, int n_in,
                              void* d_out, int out_size, void* d_ws, size_t ws_size,
                              hipStream_t stream) {
    const int*   idx      = (const int*)d_in[0];
    const float* wordlist = (const float*)d_in[1];
    float*       out      = (float*)d_out;

    int total_vec = L_TOTAL * VEC_PER_ROW;   // 16,777,216 float4s
    int block = 256;
    int grid = total_vec / block;            // 65,536 blocks
    embed_pe_kernel<<<grid, block, 0, stream>>>(idx, wordlist, out);
}

// Round 2
// 254.937 us; speedup vs baseline: 1.1202x; 1.1202x over previous
//
#include <hip/hip_runtime.h>

// Problem: Embedding_6940667150787
//   idx:      [131072] int32 in [0, 198)
//   wordlist: [198, 512] float32
//   out:      [131072, 512] float32 = wordlist[idx] + positional_encoding
//
// PE: for j in 0..254: angle = i / 10000^(2j/512);
//     pe[i, 2j] = sin(angle), pe[i, 2j+1] = cos(angle); cols 510,511 = 0.
//
// R2: each thread handles one float4-column for R=4 consecutive rows.
// Frequencies (exp2) computed once/thread; base row uses Cody-Waite sincos;
// subsequent rows advance the angle by invf via exact rotation recurrence
// (4 FMAs/pair/row). 4x fewer waves, ~2.5x fewer VALU ops per output.

#define L_TOTAL 131072
#define VEC_PER_ROW 128   // 512 floats / 4
#define R 4               // rows per thread

__device__ __forceinline__ void sincos_fast(float a, float& s, float& c) {
    // Cody-Waite reduction by 2*pi (FMA), then HW transcendental
    // (input in REVOLUTIONS).
    const float INV2PI = 0.15915493667125702f;
    const float PI2_HI = 6.2831854820251465f;
    const float PI2_LO = -1.7484555314695172e-7f;
    float k = rintf(a * INV2PI);               // exact in fp32 (k <= ~2.1e4)
    float r = fmaf(-k, PI2_HI, a);
    r = fmaf(-k, PI2_LO, r);                   // |r| <= pi, err ~4e-7 rad
    float rev = r * INV2PI;
    s = __builtin_amdgcn_sinf(rev);            // v_sin_f32: sin(rev*2pi)
    c = __builtin_amdgcn_cosf(rev);            // v_cos_f32
}

__global__ __launch_bounds__(256) void embed_pe_kernel(
    const int* __restrict__ idx,
    const float* __restrict__ wordlist,
    float* __restrict__ out)
{
    int t  = blockIdx.x * 256 + threadIdx.x;   // 0 .. (L/R)*128 - 1
    int rb = t >> 7;                           // row-block (R rows)
    int cc = t & 127;                          // float4 column
    int i0 = rb * R;

    // Inverse frequencies for pair j0=2cc (cols 4cc,4cc+1), j1=2cc+1.
    const float K = 0.051905126483205076f;     // log2(10000) / 256
    float invf0 = exp2f(-(float)(2 * cc)     * K);
    float invf1 = exp2f(-(float)(2 * cc + 1) * K);

    // Base-row sin/cos (full reduction) + per-row-step rotation (no reduction
    // needed: invf <= 1 rad, but sincos_fast handles it anyway).
    float s0, c0, s1, c1, sd0, cd0, sd1, cd1;
    sincos_fast((float)i0 * invf0, s0, c0);
    sincos_fast((float)i0 * invf1, s1, c1);
    sincos_fast(invf0, sd0, cd0);
    sincos_fast(invf1, sd1, cd1);

    bool last = (cc == VEC_PER_ROW - 1);       // j1==255 -> cols 510,511: PE=0

    int tokens[R];
#pragma unroll
    for (int k = 0; k < R; ++k) tokens[k] = idx[i0 + k];   // wave-uniform bcast

#pragma unroll
    for (int k = 0; k < R; ++k) {
        float4 w = ((const float4*)wordlist)[tokens[k] * VEC_PER_ROW + cc];
        float ps1 = last ? 0.0f : s1;
        float pc1 = last ? 0.0f : c1;
        float4 o;
        o.x = w.x + s0;
        o.y = w.y + c0;
        o.z = w.z + ps1;
        o.w = w.w + pc1;
        ((float4*)out)[(i0 + k) * VEC_PER_ROW + cc] = o;

        // rotate angles forward by one row: (s,c) <- angle + invf
        float ns0 = fmaf(s0, cd0, c0 * sd0);
        float nc0 = fmaf(c0, cd0, -s0 * sd0);
        s0 = ns0; c0 = nc0;
        float ns1 = fmaf(s1, cd1, c1 * sd1);
        float nc1 = fmaf(c1, cd1, -s1 * sd1);
        s1 = ns1; c1 = nc1;
    }
}

extern "C" void kernel_launch(void* const* d_in, const int* in_sizes, int n_in,
                              void* d_out, int out_size, void* d_ws, size_t ws_size,
                              hipStream_t stream) {
    const int*   idx      = (const int*)d_in[0];
    const float* wordlist = (const float*)d_in[1];
    float*       out      = (float*)d_out;

    int total_threads = (L_TOTAL / R) * VEC_PER_ROW;  // 4,194,304
    int block = 256;
    int grid = total_threads / block;                 // 16,384 blocks
    embed_pe_kernel<<<grid, block, 0, stream>>>(idx, wordlist, out);
}